// Round 11
// baseline (491.744 us; speedup 1.0000x reference)
//
#include <hip/hip_runtime.h>

// GAT layer, N=8192, F_IN=512, F_OUT=256. ALL tensors f32; adj int32.
// out = softmax_row(mask(leaky(s1_i+s2_j))) @ h, h = X@W, s{1,2} = h_f32@a{1,2}.
//
// R10 -> R11: harness overhead (1 GiB ws re-poison fills ~160us x2 + input
// restore) dominates dur_us; controllable kernels are all <158us. attn's
// remaining waste is 64 per-iter barriers at 1 block/CU (no co-resident cover
// for the drain). Fix: KB=256 per barrier (ITERS=32): 32 MFMA + 16 B-loads +
// 16 af ds_reads per window -> half the barrier count, deeper vmem queue.
// P dbuf 33.8 KB LDS, pad 264 shorts keeps b128 reads conflict-free.

typedef __attribute__((ext_vector_type(8))) short bf16x8;
typedef __attribute__((ext_vector_type(4))) float fx4;
typedef __attribute__((ext_vector_type(4))) int ix4;
typedef __attribute__((ext_vector_type(2))) unsigned int ux2;

#define NN 8192
#define FIN 512
#define FOUT 256
#define PS 264     // LDS P row stride (shorts): 256 + 8 pad (4-bank rotation)
#define AROWS 32   // attn rows per block

__device__ __forceinline__ unsigned short f2bf(float f) {
    unsigned int x = __float_as_uint(f);
    x += 0x7fffu + ((x >> 16) & 1u);
    return (unsigned short)(x >> 16);
}
__device__ __forceinline__ bf16x8 pack8(fx4 a, fx4 b) {
    bf16x8 r;
    r[0] = (short)f2bf(a[0]); r[1] = (short)f2bf(a[1]);
    r[2] = (short)f2bf(a[2]); r[3] = (short)f2bf(a[3]);
    r[4] = (short)f2bf(b[0]); r[5] = (short)f2bf(b[1]);
    r[6] = (short)f2bf(b[2]); r[7] = (short)f2bf(b[3]);
    return r;
}

// ---------- kernel 0: WTt[((k>>5)*256+c)*32 + (k&31)] = bf16(W[k][c]) ----------
__global__ void wt_kernel(const float* __restrict__ W,
                          unsigned short* __restrict__ WTt) {
    const int c = threadIdx.x;
    const int k = blockIdx.x;
    WTt[((size_t)(k >> 5) * 256 + c) * 32 + (k & 31)] = f2bf(W[k * FOUT + c]);
}

// ---------- kernel 1 (merged): h-tile role + adj->mask streaming role ----------
// Blocks 0..511: 16-row h tile (MFMA) + fused s1/s2. Blocks 512..8703: pack
// adj (64M int32) into 1-bit mask (8 MB), 8 independent ix4 loads/thread.
// MFMA 16x16x32: A[m=l&15][k=q*8+j], B[k=q*8+j][n=l&15], D: col=l&15, row=q*4+r.
__global__ __launch_bounds__(256) void prep_kernel(
    const float* __restrict__ X,              // 8192x512 f32
    const unsigned short* __restrict__ WTt,   // tiled 256x512 bf16
    const float* __restrict__ A,              // 512 f32 (a1|a2)
    const int* __restrict__ adj,              // 8192x8192 i32
    unsigned short* __restrict__ hTt,         // tiled 256x8192 bf16
    float* __restrict__ s1, float* __restrict__ s2,
    unsigned int* __restrict__ mask)          // 8192x256 dwords
{
    __shared__ float s1sh[4][16], s2sh[4][16];
    const int tid = threadIdx.x;

    if (blockIdx.x >= 512) {
        // ---- mask role ----
        const int g = (blockIdx.x - 512) * 256 + tid;   // 0..2M-1
        const int* base = adj + (size_t)g * 32;
        ix4 v[8];
#pragma unroll
        for (int k = 0; k < 8; ++k) v[k] = *(const ix4*)(base + k * 4);
        unsigned int m = 0;
#pragma unroll
        for (int k = 0; k < 8; ++k)
#pragma unroll
            for (int j = 0; j < 4; ++j)
                m |= (v[k][j] != 0 ? 1u : 0u) << (k * 4 + j);
        mask[g] = m;
        return;
    }

    // ---- h role ----
    const int w = tid >> 6, l = tid & 63, q = l >> 4, lr = l & 15;
    const int r0 = blockIdx.x * 16;
    const int cbase = w * 64;
    fx4 acc[4] = {};

    for (int kb = 0; kb < FIN; kb += 32) {
        const float* xp = X + (size_t)(r0 + lr) * FIN + kb + q * 8;
        bf16x8 a0 = pack8(*(const fx4*)xp, *(const fx4*)(xp + 4));
#pragma unroll
        for (int tc = 0; tc < 4; ++tc) {
            bf16x8 b = *(const bf16x8*)(WTt + ((size_t)(kb >> 5) * 256 + cbase + tc * 16 + lr) * 32 + q * 8);
            acc[tc] = __builtin_amdgcn_mfma_f32_16x16x32_bf16(a0, b, acc[tc], 0, 0, 0);
        }
    }

    // tiled hTt write
    const int jb = r0 >> 5, jo = (r0 & 31) + q * 4;
#pragma unroll
    for (int tc = 0; tc < 4; ++tc) {
        const int c = cbase + tc * 16 + lr;
        ux2 hp;
        hp.x = (unsigned)f2bf(acc[tc][0]) | ((unsigned)f2bf(acc[tc][1]) << 16);
        hp.y = (unsigned)f2bf(acc[tc][2]) | ((unsigned)f2bf(acc[tc][3]) << 16);
        *(ux2*)(hTt + ((size_t)jb * 256 + c) * 32 + jo) = hp;
    }

    // fused s1/s2 from f32 accumulators
    float p1[4] = {}, p2[4] = {};
#pragma unroll
    for (int tc = 0; tc < 4; ++tc) {
        const int c = cbase + tc * 16 + lr;
        const float a1v = A[c], a2v = A[FOUT + c];
#pragma unroll
        for (int r = 0; r < 4; ++r) {
            p1[r] += acc[tc][r] * a1v;
            p2[r] += acc[tc][r] * a2v;
        }
    }
#pragma unroll
    for (int r = 0; r < 4; ++r) {
#pragma unroll
        for (int off = 1; off < 16; off <<= 1) {
            p1[r] += __shfl_xor(p1[r], off);
            p2[r] += __shfl_xor(p2[r], off);
        }
        if (lr == 0) { s1sh[w][q * 4 + r] = p1[r]; s2sh[w][q * 4 + r] = p2[r]; }
    }
    __syncthreads();
    if (tid < 16) {
        s1[r0 + tid] = s1sh[0][tid] + s1sh[1][tid] + s1sh[2][tid] + s1sh[3][tid];
        s2[r0 + tid] = s2sh[0][tid] + s2sh[1][tid] + s2sh[2][tid] + s2sh[3][tid];
    }
}

// ---------- kernel 2: fused masked-softmax @ h, f32 out ----------
// Grid 256 (1 block/CU) x 512 thr (8 waves). 32 rows/block; wave w owns cols
// w*32..+31. Per iter (KB=256, ITERS=32): P-threads generate 16 exps each into
// dbuf LDS (A-layout); MFMA waves run 8 ks x 4 = 32 MFMAs vs 16 B-frag loads.
// Half the barriers of KB=128; mask/s2 prefetched one iter ahead.
__global__ __launch_bounds__(512) void attn_kernel(
    const unsigned int* __restrict__ mask,   // 8192 x 256 dwords
    const unsigned short* __restrict__ hTt,  // tiled 256 x 8192 bf16
    const float* __restrict__ s1,
    const float* __restrict__ s2,
    float* __restrict__ out)                 // 8192 x 256 f32
{
    __shared__ unsigned short P[2][AROWS * PS];   // 33.8 KB
    __shared__ float dsh[AROWS];

    const int tid = threadIdx.x;
    const int r0 = blockIdx.x * AROWS;

    // P-generation role: thread -> (row, 16-col group within 256-j window)
    const int prow = tid >> 4;                 // 0..31
    const int pq = tid & 15;                   // cols pq*16..+15
    const float s1v = s1[r0 + prow];
    const unsigned int* mrow = mask + (size_t)(r0 + prow) * 256;
    float denp = 0.f;

    // MFMA role
    const int w = tid >> 6, l = tid & 63, q = l >> 4, lr = l & 15;
    const int cbase = w * 32;
    fx4 acc[2][2] = {};

    unsigned int mv; fx4 s2v[4];               // prefetch registers
    auto loadP = [&](int kt) {
        mv = mrow[kt * 8 + (pq >> 1)];         // dword covers 32 j; we use 16
        const int jb = kt * 256 + pq * 16;
#pragma unroll
        for (int i = 0; i < 4; ++i) s2v[i] = *(const fx4*)(s2 + jb + i * 4);
    };
    auto calcP = [&](int b) {
        const unsigned int bits = (mv >> ((pq & 1) * 16)) & 0xFFFFu;
        unsigned short* dst = &P[b][prow * PS + pq * 16];
#pragma unroll
        for (int half = 0; half < 2; ++half) {
            bf16x8 pv;
#pragma unroll
            for (int j = 0; j < 8; ++j) {
                const int jj = half * 8 + j;
                const float s2j = s2v[jj >> 2][jj & 3];
                float t = s1v + s2j;
                float e = fmaxf(t, 0.2f * t);  // leaky_relu, alpha=0.2
                e = fminf(e, 30.f);            // overflow guard (inactive)
                const float p = ((bits >> jj) & 1u) ? __expf(e) : 0.f;
                denp += p;
                pv[j] = (short)f2bf(p);
            }
            *(bf16x8*)(dst + half * 8) = pv;   // 16B store
        }
    };

    loadP(0);
    calcP(0);
    __syncthreads();

    const int ITERS = NN / 256;   // 32
    for (int it = 0; it < ITERS; ++it) {
        if (it + 1 < ITERS) loadP(it + 1);
        // B-frags for the full 256-j window (16 coalesced 1KB wave loads)
        bf16x8 B[8][2];
#pragma unroll
        for (int ks = 0; ks < 8; ++ks)
#pragma unroll
            for (int tc = 0; tc < 2; ++tc)
                B[ks][tc] = *(const bf16x8*)(hTt + ((size_t)(it * 8 + ks) * 256 + cbase + tc * 16 + lr) * 32 + q * 8);

        const unsigned short* Pb = P[it & 1];
#pragma unroll
        for (int ks = 0; ks < 8; ++ks) {
            bf16x8 af0 = *(const bf16x8*)(Pb + lr * PS + ks * 32 + q * 8);
            bf16x8 af1 = *(const bf16x8*)(Pb + (16 + lr) * PS + ks * 32 + q * 8);
            acc[0][0] = __builtin_amdgcn_mfma_f32_16x16x32_bf16(af0, B[ks][0], acc[0][0], 0, 0, 0);
            acc[0][1] = __builtin_amdgcn_mfma_f32_16x16x32_bf16(af0, B[ks][1], acc[0][1], 0, 0, 0);
            acc[1][0] = __builtin_amdgcn_mfma_f32_16x16x32_bf16(af1, B[ks][0], acc[1][0], 0, 0, 0);
            acc[1][1] = __builtin_amdgcn_mfma_f32_16x16x32_bf16(af1, B[ks][1], acc[1][1], 0, 0, 0);
        }
        if (it + 1 < ITERS) calcP((it + 1) & 1);
        __syncthreads();
    }

    // den: reduce over the 16 lanes sharing a row
    float v = denp;
    v += __shfl_xor(v, 1);
    v += __shfl_xor(v, 2);
    v += __shfl_xor(v, 4);
    v += __shfl_xor(v, 8);
    if (pq == 0) dsh[prow] = v;
    __syncthreads();

#pragma unroll
    for (int mg = 0; mg < 2; ++mg) {
#pragma unroll
        for (int r = 0; r < 4; ++r) {
            const int row = mg * 16 + q * 4 + r;
            const float dinv = 1.0f / fmaxf(dsh[row], 1e-30f);
#pragma unroll
            for (int tc = 0; tc < 2; ++tc) {
                out[(size_t)(r0 + row) * FOUT + cbase + tc * 16 + lr] = acc[mg][tc][r] * dinv;
            }
        }
    }
}

extern "C" void kernel_launch(void* const* d_in, const int* in_sizes, int n_in,
                              void* d_out, int out_size, void* d_ws, size_t ws_size,
                              hipStream_t stream) {
    const float *X = nullptr, *W = nullptr, *A = nullptr;
    const int* adj = nullptr;
    for (int i = 0; i < n_in; ++i) {
        switch (in_sizes[i]) {
            case NN * FIN:   X = (const float*)d_in[i]; break;
            case FIN * FOUT: W = (const float*)d_in[i]; break;
            case 2 * FOUT:   A = (const float*)d_in[i]; break;
            case NN * NN:    adj = (const int*)d_in[i]; break;
        }
    }
    if (!X) X = (const float*)d_in[0];
    if (!W) W = (const float*)d_in[1];
    if (!A) A = (const float*)d_in[2];
    if (!adj) adj = (const int*)d_in[3];
    float* out = (float*)d_out;

    // ws layout (13.25 MB of the 1 GiB ws):
    char* ws = (char*)d_ws;
    float* s1 = (float*)ws;                                 // 32 KB
    float* s2 = (float*)(ws + 32768);                       // 32 KB
    unsigned short* WTt = (unsigned short*)(ws + 98304);    // 256 KB
    unsigned short* hTt = (unsigned short*)(ws + 360448);   // 4 MB
    unsigned int* mask = (unsigned int*)(ws + 5242880);     // 8 MB

    wt_kernel<<<512, 256, 0, stream>>>(W, WTt);
    prep_kernel<<<512 + 8192, 256, 0, stream>>>(X, WTt, A, adj, hTt, s1, s2, mask);
    attn_kernel<<<NN / AROWS, 512, 0, stream>>>(mask, hTt, s1, s2, out);
}